// Round 3
// baseline (1461.727 us; speedup 1.0000x reference)
//
#include <hip/hip_runtime.h>
#include <cmath>

#define B_   8
#define CI_  3
#define CM_  21
#define H_   128
#define W_   128
#define K_   32
#define PAD_ 8
#define PW_  144
#define PH_  144
#define NC_  3   // mask channels per block in iter kernel (21 = 7 groups of 3)

typedef float f4 __attribute__((ext_vector_type(4)));

struct PosSoft { float v[K_]; };

// shifted window: elements [S .. S+3] of concat(A,B) (A = cols s-4..s-1, B = s..s+3)
template<int S>
__device__ __forceinline__ f4 shw(f4 A, f4 B) {
  if constexpr (S == 0) return A;
  else if constexpr (S == 1) return (f4){A.y, A.z, A.w, B.x};
  else if constexpr (S == 2) return (f4){A.z, A.w, B.x, B.y};
  else                       return (f4){A.w, B.x, B.y, B.z};
}

// aligned f4 load at compile-time float offset -> single global_load_dwordx4
__device__ __forceinline__ f4 ldq(const float* __restrict__ p, int off) {
  return *reinterpret_cast<const f4*>(p + off);
}

// ---------------------------------------------------------------------------
// Phase A: per-pixel affinity (softmax over K=32) + constant position term.
// Output layout: aff[b][i][k][j]  (k-major per row, j contiguous).
// ---------------------------------------------------------------------------
__global__ __launch_bounds__(128) void aff_kernel(const float* __restrict__ imgs,
                                                  float* __restrict__ aff,
                                                  PosSoft ps) {
  constexpr int OI[8] = {-1,-1,-1, 0, 0, 1, 1, 1};
  constexpr int OJ[8] = {-1, 0, 1,-1, 1,-1, 0, 1};
  const int j = threadIdx.x;
  const int i = blockIdx.x;
  const int b = blockIdx.y;
  const float* img = imgs + (size_t)b * CI_ * H_ * W_;

  float ctr[CI_];
#pragma unroll
  for (int c = 0; c < CI_; ++c) ctr[c] = img[c * H_ * W_ + i * W_ + j];

  float s[CI_] = {0.f, 0.f, 0.f}, s2[CI_] = {0.f, 0.f, 0.f};
#pragma unroll
  for (int k = 0; k < K_; ++k) {
    const int d  = 1 << (k >> 3);
    const int ci = min(max(i + OI[k & 7] * d, 0), H_ - 1);
    const int cj = min(max(j + OJ[k & 7] * d, 0), W_ - 1);
#pragma unroll
    for (int c = 0; c < CI_; ++c) {
      float v = img[c * H_ * W_ + ci * W_ + cj];
      s[c] += v; s2[c] += v * v;
    }
  }

  float inv[CI_];
#pragma unroll
  for (int c = 0; c < CI_; ++c) {
    float mean = s[c] * (1.f / K_);
    float var  = (s2[c] - (float)K_ * mean * mean) * (1.f / (K_ - 1));
    var = fmaxf(var, 0.f);
    inv[c] = 1.f / ((sqrtf(var) + 1e-8f) * 0.3f);
  }

  float araw[K_];
#pragma unroll
  for (int k = 0; k < K_; ++k) {
    const int d  = 1 << (k >> 3);
    const int ci = min(max(i + OI[k & 7] * d, 0), H_ - 1);
    const int cj = min(max(j + OJ[k & 7] * d, 0), W_ - 1);
    float t = 0.f;
#pragma unroll
    for (int c = 0; c < CI_; ++c) {
      float v  = img[c * H_ * W_ + ci * W_ + cj];
      float dd = fabsf(v - ctr[c]) * inv[c];
      t += dd * dd;
    }
    araw[k] = -t * (1.f / CI_);
  }

  float m = araw[0];
#pragma unroll
  for (int k = 1; k < K_; ++k) m = fmaxf(m, araw[k]);
  float sum = 0.f;
#pragma unroll
  for (int k = 0; k < K_; ++k) { float e = __expf(araw[k] - m); araw[k] = e; sum += e; }
  const float rs = 1.f / sum;

  float* ap = aff + ((size_t)(b * H_ + i) * K_) * W_ + j;
#pragma unroll
  for (int k = 0; k < K_; ++k) ap[k * W_] = araw[k] * rs + ps.v[k];
}

// ---------------------------------------------------------------------------
// Pad masks into edge-replicated 144x144 planes.
// ---------------------------------------------------------------------------
__global__ void pad_kernel(const float* __restrict__ src, float* __restrict__ dst,
                           int total) {
  int idx = blockIdx.x * blockDim.x + threadIdx.x;
  if (idx >= total) return;
  int pj = idx % PW_;
  int t  = idx / PW_;
  int pi = t % PH_;
  int p  = t / PH_;
  int i = min(max(pi - PAD_, 0), H_ - 1);
  int j = min(max(pj - PAD_, 0), W_ - 1);
  dst[idx] = src[(size_t)p * (H_ * W_) + i * W_ + j];
}

// ---- vertical+diagonal taps for dilation D; aligned loads + reg swizzle ----
// bm[c] points at (row i-4, col j0) of channel c (padded coords);
// bp[c] at (row i+4, col j0). All offsets are 13-bit immediates.
template<int D>
__device__ __forceinline__ void vgrp(const float* __restrict__ abD,
                                     const float* const* bm, const float* const* bp,
                                     f4* acc) {
  f4 au0 = ldq(abD, 0),       au1 = ldq(abD, 1 * W_), au2 = ldq(abD, 2 * W_);
  f4 ad0 = ldq(abD, 5 * W_),  ad1 = ldq(abD, 6 * W_), ad2 = ldq(abD, 7 * W_);
  constexpr int RU = (4 - D) * PW_;   // row -D from bm
  constexpr int RD = (D - 4) * PW_;   // row +D from bp
  constexpr int TT = (D == 8) ? 8 : 4;
#pragma unroll
  for (int c = 0; c < NC_; ++c) {
    f4 ua = ldq(bm[c], RU - TT), ub = ldq(bm[c], RU), uc = ldq(bm[c], RU + TT);
    f4 da = ldq(bp[c], RD - TT), db = ldq(bp[c], RD), dc = ldq(bp[c], RD + TT);
    if constexpr (D <= 2) {
      acc[c] += au0 * shw<(4 - D) & 3>(ua, ub) + au1 * ub + au2 * shw<D>(ub, uc);
      acc[c] += ad0 * shw<(4 - D) & 3>(da, db) + ad1 * db + ad2 * shw<D>(db, dc);
    } else {
      acc[c] += au0 * ua + au1 * ub + au2 * uc;
      acc[c] += ad0 * da + ad1 * db + ad2 * dc;
    }
  }
}

// ---------------------------------------------------------------------------
// Propagation step: direct global loads (R1 schedule), aligned addressing.
// Block 128 thr = 4 rows x 32 col-quads; grid (32, 7, 8).
// ---------------------------------------------------------------------------
template <int PADOUT>
__global__ __launch_bounds__(128, 4) void iter_kernel(const float* __restrict__ src,
                                                      const float* __restrict__ aff,
                                                      float* __restrict__ dst) {
  const int tid = threadIdx.x;
  const int j0  = (tid & 31) * 4;
  const int i   = blockIdx.x * 4 + (tid >> 5);
  const int c0  = blockIdx.y * NC_;
  const int b   = blockIdx.z;

  constexpr int CHP = PH_ * PW_;
  const float* rp0 = src + (size_t)(b * CM_ + c0) * CHP + (i + PAD_) * PW_ + (j0 + PAD_);

  const float* bm[NC_];
  const float* bp[NC_];
#pragma unroll
  for (int c = 0; c < NC_; ++c) {
    bm[c] = rp0 + c * CHP - 4 * PW_;
    bp[c] = rp0 + c * CHP + 4 * PW_;
  }

  const float* ab0 = aff + ((size_t)(b * H_ + i) * K_) * W_ + j0;
  const float* ab1 = ab0 +  8 * W_;
  const float* ab2 = ab0 + 16 * W_;
  const float* ab3 = ab0 + 24 * W_;

  f4 acc[NC_];
#pragma unroll
  for (int c = 0; c < NC_; ++c) acc[c] = (f4){0.f, 0.f, 0.f, 0.f};

  // ---- horizontal taps (0, +-d) all dilations: center row, 5 aligned f4/ch
  {
    f4 a1m = ldq(ab0, 3 * W_), a1p = ldq(ab0, 4 * W_);
    f4 a2m = ldq(ab1, 3 * W_), a2p = ldq(ab1, 4 * W_);
    f4 a4m = ldq(ab2, 3 * W_), a4p = ldq(ab2, 4 * W_);
    f4 a8m = ldq(ab3, 3 * W_), a8p = ldq(ab3, 4 * W_);
#pragma unroll
    for (int c = 0; c < NC_; ++c) {
      constexpr int R0 = 4 * PW_;   // center row from bm
      f4 m_2 = ldq(bm[c], R0 - 8), m_1 = ldq(bm[c], R0 - 4), m0 = ldq(bm[c], R0);
      f4 m1  = ldq(bm[c], R0 + 4), m2  = ldq(bm[c], R0 + 8);
      acc[c] += a1m * shw<3>(m_1, m0) + a1p * shw<1>(m0, m1);
      acc[c] += a2m * shw<2>(m_1, m0) + a2p * shw<2>(m0, m1);
      acc[c] += a4m * m_1 + a4p * m1;
      acc[c] += a8m * m_2 + a8p * m2;
    }
  }

  // ---- vertical + diagonal taps per dilation
  vgrp<1>(ab0, bm, bp, acc);
  vgrp<2>(ab1, bm, bp, acc);
  vgrp<4>(ab2, bm, bp, acc);
  vgrp<8>(ab3, bm, bp, acc);

  // ---- epilogue
  if (PADOUT) {
    const int pr = i + PAD_;
    const int r0 = (i == 0)      ? 0         : pr;
    const int r1 = (i == H_ - 1) ? (PH_ - 1) : pr;
#pragma unroll
    for (int c = 0; c < NC_; ++c) {
      float* dc = dst + ((size_t)(b * CM_ + c0 + c)) * CHP;
      for (int r = r0; r <= r1; ++r) {
        float* row = dc + r * PW_;
        *reinterpret_cast<f4*>(row + PAD_ + j0) = acc[c];
        if (j0 == 0) {
          for (int x = 0; x < PAD_; ++x) row[x] = acc[c].x;
        }
        if (j0 == W_ - 4) {
          for (int x = PW_ - PAD_; x < PW_; ++x) row[x] = acc[c].w;
        }
      }
    }
  } else {
    float* dc = dst + ((size_t)(b * CM_ + c0)) * (H_ * W_) + (size_t)i * W_ + j0;
#pragma unroll
    for (int c = 0; c < NC_; ++c) {
      *reinterpret_cast<f4*>(dc + (size_t)c * (H_ * W_)) = acc[c];
    }
  }
}

// ---------------------------------------------------------------------------
extern "C" void kernel_launch(void* const* d_in, const int* in_sizes, int n_in,
                              void* d_out, int out_size, void* d_ws, size_t ws_size,
                              hipStream_t stream) {
  const float* imgs  = (const float*)d_in[0];
  const float* masks = (const float*)d_in[1];
  float* out = (float*)d_out;

  char* ws = (char*)d_ws;
  const size_t affBytes = (size_t)B_ * K_ * H_ * W_ * sizeof(float);
  const size_t padBytes = (size_t)B_ * CM_ * PH_ * PW_ * sizeof(float);
  float* aff = (float*)ws;
  float* P0  = (float*)(ws + affBytes);
  float* P1  = (float*)(ws + affBytes + padBytes);

  PosSoft ps;
  {
    const double pv[8] = {1.4142135623730951, 1.0, 1.4142135623730951, 1.0,
                          1.0, 1.4142135623730951, 1.0, 1.4142135623730951};
    double pos[K_];
    for (int di = 0; di < 4; ++di) {
      double d = (double)(1 << di);
      for (int o = 0; o < 8; ++o) pos[di * 8 + o] = pv[o] * d;
    }
    double mean = 0; for (int k = 0; k < K_; ++k) mean += pos[k]; mean /= K_;
    double var = 0;  for (int k = 0; k < K_; ++k) { double dd = pos[k] - mean; var += dd * dd; }
    var /= (K_ - 1);
    double sd = sqrt(var);
    double pa[K_]; double m = -1e300;
    for (int k = 0; k < K_; ++k) {
      double r = pos[k] / ((sd + 1e-8) * 0.3);
      pa[k] = -(r * r);
      if (pa[k] > m) m = pa[k];
    }
    double es = 0; for (int k = 0; k < K_; ++k) { pa[k] = exp(pa[k] - m); es += pa[k]; }
    for (int k = 0; k < K_; ++k) ps.v[k] = (float)(0.01 * pa[k] / es);
  }

  aff_kernel<<<dim3(H_, B_), 128, 0, stream>>>(imgs, aff, ps);

  const int total = B_ * CM_ * PH_ * PW_;
  pad_kernel<<<(total + 255) / 256, 256, 0, stream>>>(masks, P0, total);

  dim3 grid(H_ / 4, CM_ / NC_, B_);   // 32 x 7 x 8 = 1792 blocks
  float* s = P0;
  float* d = P1;
  for (int it = 0; it < 9; ++it) {
    iter_kernel<1><<<grid, 128, 0, stream>>>(s, aff, d);
    float* t = s; s = d; d = t;
  }
  iter_kernel<0><<<grid, 128, 0, stream>>>(s, aff, out);
}

// Round 4
// 250.972 us; speedup vs baseline: 5.8243x; 5.8243x over previous
//
#include <hip/hip_runtime.h>
#include <cmath>

#define B_   8
#define CI_  3
#define CM_  21
#define H_   128
#define W_   128
#define K_   32
#define PAD_ 8
#define PW_  144
#define PH_  144
#define NC_  3   // mask channels per block in iter kernel (21 = 7 groups of 3)

typedef float f4 __attribute__((ext_vector_type(4)));

struct PosSoft { float v[K_]; };

// shifted window: elements [S .. S+3] of concat(A,B); compiles to register
// component selection inside the consuming v_fma (no movs needed).
template<int S>
__device__ __forceinline__ f4 shw(f4 A, f4 B) {
  if constexpr (S == 0) return A;
  else if constexpr (S == 1) return (f4){A.y, A.z, A.w, B.x};
  else if constexpr (S == 2) return (f4){A.z, A.w, B.x, B.y};
  else                       return (f4){A.w, B.x, B.y, B.z};
}

// aligned f4 load at compile-time float offset -> single global_load_dwordx4
__device__ __forceinline__ f4 ldq(const float* p, int off) {
  return *reinterpret_cast<const f4*>(p + off);
}

// ---------------------------------------------------------------------------
// Phase A: per-pixel affinity (softmax over K=32) + constant position term.
// Output layout: aff[b][i][k][j]  (k-major per row, j contiguous).
// ---------------------------------------------------------------------------
__global__ __launch_bounds__(128) void aff_kernel(const float* __restrict__ imgs,
                                                  float* __restrict__ aff,
                                                  PosSoft ps) {
  constexpr int OI[8] = {-1,-1,-1, 0, 0, 1, 1, 1};
  constexpr int OJ[8] = {-1, 0, 1,-1, 1,-1, 0, 1};
  const int j = threadIdx.x;
  const int i = blockIdx.x;
  const int b = blockIdx.y;
  const float* img = imgs + (size_t)b * CI_ * H_ * W_;

  float ctr[CI_];
#pragma unroll
  for (int c = 0; c < CI_; ++c) ctr[c] = img[c * H_ * W_ + i * W_ + j];

  float s[CI_] = {0.f, 0.f, 0.f}, s2[CI_] = {0.f, 0.f, 0.f};
#pragma unroll
  for (int k = 0; k < K_; ++k) {
    const int d  = 1 << (k >> 3);
    const int ci = min(max(i + OI[k & 7] * d, 0), H_ - 1);
    const int cj = min(max(j + OJ[k & 7] * d, 0), W_ - 1);
#pragma unroll
    for (int c = 0; c < CI_; ++c) {
      float v = img[c * H_ * W_ + ci * W_ + cj];
      s[c] += v; s2[c] += v * v;
    }
  }

  float inv[CI_];
#pragma unroll
  for (int c = 0; c < CI_; ++c) {
    float mean = s[c] * (1.f / K_);
    float var  = (s2[c] - (float)K_ * mean * mean) * (1.f / (K_ - 1));
    var = fmaxf(var, 0.f);
    inv[c] = 1.f / ((sqrtf(var) + 1e-8f) * 0.3f);
  }

  float araw[K_];
#pragma unroll
  for (int k = 0; k < K_; ++k) {
    const int d  = 1 << (k >> 3);
    const int ci = min(max(i + OI[k & 7] * d, 0), H_ - 1);
    const int cj = min(max(j + OJ[k & 7] * d, 0), W_ - 1);
    float t = 0.f;
#pragma unroll
    for (int c = 0; c < CI_; ++c) {
      float v  = img[c * H_ * W_ + ci * W_ + cj];
      float dd = fabsf(v - ctr[c]) * inv[c];
      t += dd * dd;
    }
    araw[k] = -t * (1.f / CI_);
  }

  float m = araw[0];
#pragma unroll
  for (int k = 1; k < K_; ++k) m = fmaxf(m, araw[k]);
  float sum = 0.f;
#pragma unroll
  for (int k = 0; k < K_; ++k) { float e = __expf(araw[k] - m); araw[k] = e; sum += e; }
  const float rs = 1.f / sum;

  float* ap = aff + ((size_t)(b * H_ + i) * K_) * W_ + j;
#pragma unroll
  for (int k = 0; k < K_; ++k) ap[k * W_] = araw[k] * rs + ps.v[k];
}

// ---------------------------------------------------------------------------
// Pad masks into edge-replicated 144x144 planes.
// ---------------------------------------------------------------------------
__global__ void pad_kernel(const float* __restrict__ src, float* __restrict__ dst,
                           int total) {
  int idx = blockIdx.x * blockDim.x + threadIdx.x;
  if (idx >= total) return;
  int pj = idx % PW_;
  int t  = idx / PW_;
  int pi = t % PH_;
  int p  = t / PH_;
  int i = min(max(pi - PAD_, 0), H_ - 1);
  int j = min(max(pj - PAD_, 0), W_ - 1);
  dst[idx] = src[(size_t)p * (H_ * W_) + i * W_ + j];
}

// ---------------------------------------------------------------------------
// Per-channel taps for one dilation. PM points at (row i-4, col j0), PP at
// (row i+4, col j0) of the channel. All offsets are compile-time immediates
// within +-4095 bytes. Shifted (D=1,2) variant swizzles register components;
// aligned (D=4,8) variant loads directly. NO address-taken locals anywhere.
// ---------------------------------------------------------------------------
#define CH_S(D, SM, PM, PP, A0, A1, A2, AHM, AHP, A5, A6, A7, ACC) do {        \
    f4 ua = ldq(PM, (4 - D) * PW_ - 4), ub = ldq(PM, (4 - D) * PW_),           \
       uc = ldq(PM, (4 - D) * PW_ + 4);                                        \
    f4 hm = ldq(PM, 4 * PW_ - 4), h0 = ldq(PM, 4 * PW_),                       \
       hp = ldq(PM, 4 * PW_ + 4);                                              \
    f4 da = ldq(PP, (D - 4) * PW_ - 4), db = ldq(PP, (D - 4) * PW_),           \
       dc = ldq(PP, (D - 4) * PW_ + 4);                                        \
    ACC += A0 * shw<SM>(ua, ub) + A1 * ub + A2 * shw<D>(ub, uc);               \
    ACC += AHM * shw<SM>(hm, h0) + AHP * shw<D>(h0, hp);                       \
    ACC += A5 * shw<SM>(da, db) + A6 * db + A7 * shw<D>(db, dc);               \
  } while (0)

#define CH_A(D, PM, PP, A0, A1, A2, AHM, AHP, A5, A6, A7, ACC) do {            \
    ACC += A0 * ldq(PM, (4 - D) * PW_ - D) + A1 * ldq(PM, (4 - D) * PW_)       \
         + A2 * ldq(PM, (4 - D) * PW_ + D);                                    \
    ACC += AHM * ldq(PM, 4 * PW_ - D) + AHP * ldq(PM, 4 * PW_ + D);            \
    ACC += A5 * ldq(PP, (D - 4) * PW_ - D) + A6 * ldq(PP, (D - 4) * PW_)       \
         + A7 * ldq(PP, (D - 4) * PW_ + D);                                    \
  } while (0)

#define DGROUP_S(D, SM, AB) do {                                               \
    f4 a0 = ldq(AB, 0), a1 = ldq(AB, W_), a2 = ldq(AB, 2 * W_);                \
    f4 ahm = ldq(AB, 3 * W_), ahp = ldq(AB, 4 * W_);                           \
    f4 a5 = ldq(AB, 5 * W_), a6 = ldq(AB, 6 * W_), a7 = ldq(AB, 7 * W_);       \
    CH_S(D, SM, p0m, p0p, a0, a1, a2, ahm, ahp, a5, a6, a7, acc0);             \
    CH_S(D, SM, p1m, p1p, a0, a1, a2, ahm, ahp, a5, a6, a7, acc1);             \
    CH_S(D, SM, p2m, p2p, a0, a1, a2, ahm, ahp, a5, a6, a7, acc2);             \
  } while (0)

#define DGROUP_A(D, AB) do {                                                   \
    f4 a0 = ldq(AB, 0), a1 = ldq(AB, W_), a2 = ldq(AB, 2 * W_);                \
    f4 ahm = ldq(AB, 3 * W_), ahp = ldq(AB, 4 * W_);                           \
    f4 a5 = ldq(AB, 5 * W_), a6 = ldq(AB, 6 * W_), a7 = ldq(AB, 7 * W_);       \
    CH_A(D, p0m, p0p, a0, a1, a2, ahm, ahp, a5, a6, a7, acc0);                 \
    CH_A(D, p1m, p1p, a0, a1, a2, ahm, ahp, a5, a6, a7, acc1);                 \
    CH_A(D, p2m, p2p, a0, a1, a2, ahm, ahp, a5, a6, a7, acc2);                 \
  } while (0)

// ---------------------------------------------------------------------------
// Propagation step. Block 128 thr = 4 rows x 32 col-quads, 3 channels.
// Grid 1792 (1-D), XCD-pinned: bid = b + 8*(tile*7 + grp) so batch b -> XCD b,
// aff-sharing channel groups are consecutive same-XCD dispatches.
// ---------------------------------------------------------------------------
template <int PADOUT>
__global__ __launch_bounds__(128, 3) void iter_kernel(const float* __restrict__ src,
                                                      const float* __restrict__ aff,
                                                      float* __restrict__ dst) {
  const int bid  = blockIdx.x;
  const int b    = bid & 7;
  const int t    = bid >> 3;
  const int grp  = t % 7;
  const int tile = t / 7;

  const int tid = threadIdx.x;
  const int j0  = (tid & 31) * 4;
  const int i   = tile * 4 + (tid >> 5);
  const int c0  = grp * NC_;

  constexpr int CHP = PH_ * PW_;
  const float* base = src + (size_t)(b * CM_ + c0) * CHP + (i + PAD_) * PW_ + (j0 + PAD_);
  const float* p0m = base           - 4 * PW_;
  const float* p0p = base           + 4 * PW_;
  const float* p1m = base +     CHP - 4 * PW_;
  const float* p1p = base +     CHP + 4 * PW_;
  const float* p2m = base + 2 * CHP - 4 * PW_;
  const float* p2p = base + 2 * CHP + 4 * PW_;

  const float* ab0 = aff + ((size_t)(b * H_ + i) * K_) * W_ + j0;
  const float* ab1 = ab0 +  8 * W_;
  const float* ab2 = ab0 + 16 * W_;
  const float* ab3 = ab0 + 24 * W_;

  f4 acc0 = (f4){0.f, 0.f, 0.f, 0.f};
  f4 acc1 = (f4){0.f, 0.f, 0.f, 0.f};
  f4 acc2 = (f4){0.f, 0.f, 0.f, 0.f};

  DGROUP_S(1, 3, ab0);
  DGROUP_S(2, 2, ab1);
  DGROUP_A(4, ab2);
  DGROUP_A(8, ab3);

  // ---- epilogue
  if (PADOUT) {
    const int pr = i + PAD_;
    const int r0 = (i == 0)      ? 0         : pr;
    const int r1 = (i == H_ - 1) ? (PH_ - 1) : pr;
    float* d0 = dst + ((size_t)(b * CM_ + c0 + 0)) * CHP;
    float* d1 = dst + ((size_t)(b * CM_ + c0 + 1)) * CHP;
    float* d2 = dst + ((size_t)(b * CM_ + c0 + 2)) * CHP;
    for (int r = r0; r <= r1; ++r) {
      float* row0 = d0 + r * PW_;
      float* row1 = d1 + r * PW_;
      float* row2 = d2 + r * PW_;
      *reinterpret_cast<f4*>(row0 + PAD_ + j0) = acc0;
      *reinterpret_cast<f4*>(row1 + PAD_ + j0) = acc1;
      *reinterpret_cast<f4*>(row2 + PAD_ + j0) = acc2;
      if (j0 == 0) {
        f4 s0 = (f4){acc0.x, acc0.x, acc0.x, acc0.x};
        f4 s1 = (f4){acc1.x, acc1.x, acc1.x, acc1.x};
        f4 s2 = (f4){acc2.x, acc2.x, acc2.x, acc2.x};
        *reinterpret_cast<f4*>(row0) = s0; *reinterpret_cast<f4*>(row0 + 4) = s0;
        *reinterpret_cast<f4*>(row1) = s1; *reinterpret_cast<f4*>(row1 + 4) = s1;
        *reinterpret_cast<f4*>(row2) = s2; *reinterpret_cast<f4*>(row2 + 4) = s2;
      }
      if (j0 == W_ - 4) {
        f4 s0 = (f4){acc0.w, acc0.w, acc0.w, acc0.w};
        f4 s1 = (f4){acc1.w, acc1.w, acc1.w, acc1.w};
        f4 s2 = (f4){acc2.w, acc2.w, acc2.w, acc2.w};
        *reinterpret_cast<f4*>(row0 + PW_ - 8) = s0; *reinterpret_cast<f4*>(row0 + PW_ - 4) = s0;
        *reinterpret_cast<f4*>(row1 + PW_ - 8) = s1; *reinterpret_cast<f4*>(row1 + PW_ - 4) = s1;
        *reinterpret_cast<f4*>(row2 + PW_ - 8) = s2; *reinterpret_cast<f4*>(row2 + PW_ - 4) = s2;
      }
    }
  } else {
    float* dc = dst + ((size_t)(b * CM_ + c0)) * (H_ * W_) + (size_t)i * W_ + j0;
    *reinterpret_cast<f4*>(dc)                    = acc0;
    *reinterpret_cast<f4*>(dc +     (H_ * W_))    = acc1;
    *reinterpret_cast<f4*>(dc + 2 * (H_ * W_))    = acc2;
  }
}

// ---------------------------------------------------------------------------
extern "C" void kernel_launch(void* const* d_in, const int* in_sizes, int n_in,
                              void* d_out, int out_size, void* d_ws, size_t ws_size,
                              hipStream_t stream) {
  const float* imgs  = (const float*)d_in[0];
  const float* masks = (const float*)d_in[1];
  float* out = (float*)d_out;

  char* ws = (char*)d_ws;
  const size_t affBytes = (size_t)B_ * K_ * H_ * W_ * sizeof(float);
  const size_t padBytes = (size_t)B_ * CM_ * PH_ * PW_ * sizeof(float);
  float* aff = (float*)ws;
  float* P0  = (float*)(ws + affBytes);
  float* P1  = (float*)(ws + affBytes + padBytes);

  PosSoft ps;
  {
    const double pv[8] = {1.4142135623730951, 1.0, 1.4142135623730951, 1.0,
                          1.0, 1.4142135623730951, 1.0, 1.4142135623730951};
    double pos[K_];
    for (int di = 0; di < 4; ++di) {
      double d = (double)(1 << di);
      for (int o = 0; o < 8; ++o) pos[di * 8 + o] = pv[o] * d;
    }
    double mean = 0; for (int k = 0; k < K_; ++k) mean += pos[k]; mean /= K_;
    double var = 0;  for (int k = 0; k < K_; ++k) { double dd = pos[k] - mean; var += dd * dd; }
    var /= (K_ - 1);
    double sd = sqrt(var);
    double pa[K_]; double m = -1e300;
    for (int k = 0; k < K_; ++k) {
      double r = pos[k] / ((sd + 1e-8) * 0.3);
      pa[k] = -(r * r);
      if (pa[k] > m) m = pa[k];
    }
    double es = 0; for (int k = 0; k < K_; ++k) { pa[k] = exp(pa[k] - m); es += pa[k]; }
    for (int k = 0; k < K_; ++k) ps.v[k] = (float)(0.01 * pa[k] / es);
  }

  aff_kernel<<<dim3(H_, B_), 128, 0, stream>>>(imgs, aff, ps);

  const int total = B_ * CM_ * PH_ * PW_;
  pad_kernel<<<(total + 255) / 256, 256, 0, stream>>>(masks, P0, total);

  const int nblk = B_ * 7 * (H_ / 4);   // 1792, XCD-pinned decode in kernel
  float* s = P0;
  float* d = P1;
  for (int it = 0; it < 9; ++it) {
    iter_kernel<1><<<nblk, 128, 0, stream>>>(s, aff, d);
    float* t = s; s = d; d = t;
  }
  iter_kernel<0><<<nblk, 128, 0, stream>>>(s, aff, out);
}

// Round 5
// 229.846 us; speedup vs baseline: 6.3596x; 1.0919x over previous
//
#include <hip/hip_runtime.h>
#include <cmath>

#define B_   8
#define CI_  3
#define CM_  21
#define H_   128
#define W_   128
#define K_   32
#define PAD_ 8
#define PW_  144
#define PH_  144
#define NC_  3   // mask channels per block in iter kernel (21 = 7 groups of 3)

typedef float f4 __attribute__((ext_vector_type(4)));

struct PosSoft { float v[K_]; };

// shifted window: elements [S .. S+3] of concat(A,B); pure register
// component selection feeding the v_fma operands.
template<int S>
__device__ __forceinline__ f4 shw(f4 A, f4 B) {
  if constexpr (S == 0) return A;
  else if constexpr (S == 1) return (f4){A.y, A.z, A.w, B.x};
  else if constexpr (S == 2) return (f4){A.z, A.w, B.x, B.y};
  else                       return (f4){A.w, B.x, B.y, B.z};
}

// aligned f4 load at compile-time float offset -> single global_load_dwordx4
__device__ __forceinline__ f4 ldq(const float* p, int off) {
  return *reinterpret_cast<const f4*>(p + off);
}

// ---------------------------------------------------------------------------
// Phase A: per-pixel affinity (softmax over K=32) + constant position term.
// Output layout: aff[b][i][k][j]  (k-major per row, j contiguous).
// ---------------------------------------------------------------------------
__global__ __launch_bounds__(128) void aff_kernel(const float* __restrict__ imgs,
                                                  float* __restrict__ aff,
                                                  PosSoft ps) {
  constexpr int OI[8] = {-1,-1,-1, 0, 0, 1, 1, 1};
  constexpr int OJ[8] = {-1, 0, 1,-1, 1,-1, 0, 1};
  const int j = threadIdx.x;
  const int i = blockIdx.x;
  const int b = blockIdx.y;
  const float* img = imgs + (size_t)b * CI_ * H_ * W_;

  float ctr[CI_];
#pragma unroll
  for (int c = 0; c < CI_; ++c) ctr[c] = img[c * H_ * W_ + i * W_ + j];

  float s[CI_] = {0.f, 0.f, 0.f}, s2[CI_] = {0.f, 0.f, 0.f};
#pragma unroll
  for (int k = 0; k < K_; ++k) {
    const int d  = 1 << (k >> 3);
    const int ci = min(max(i + OI[k & 7] * d, 0), H_ - 1);
    const int cj = min(max(j + OJ[k & 7] * d, 0), W_ - 1);
#pragma unroll
    for (int c = 0; c < CI_; ++c) {
      float v = img[c * H_ * W_ + ci * W_ + cj];
      s[c] += v; s2[c] += v * v;
    }
  }

  float inv[CI_];
#pragma unroll
  for (int c = 0; c < CI_; ++c) {
    float mean = s[c] * (1.f / K_);
    float var  = (s2[c] - (float)K_ * mean * mean) * (1.f / (K_ - 1));
    var = fmaxf(var, 0.f);
    inv[c] = 1.f / ((sqrtf(var) + 1e-8f) * 0.3f);
  }

  float araw[K_];
#pragma unroll
  for (int k = 0; k < K_; ++k) {
    const int d  = 1 << (k >> 3);
    const int ci = min(max(i + OI[k & 7] * d, 0), H_ - 1);
    const int cj = min(max(j + OJ[k & 7] * d, 0), W_ - 1);
    float t = 0.f;
#pragma unroll
    for (int c = 0; c < CI_; ++c) {
      float v  = img[c * H_ * W_ + ci * W_ + cj];
      float dd = fabsf(v - ctr[c]) * inv[c];
      t += dd * dd;
    }
    araw[k] = -t * (1.f / CI_);
  }

  float m = araw[0];
#pragma unroll
  for (int k = 1; k < K_; ++k) m = fmaxf(m, araw[k]);
  float sum = 0.f;
#pragma unroll
  for (int k = 0; k < K_; ++k) { float e = __expf(araw[k] - m); araw[k] = e; sum += e; }
  const float rs = 1.f / sum;

  float* ap = aff + ((size_t)(b * H_ + i) * K_) * W_ + j;
#pragma unroll
  for (int k = 0; k < K_; ++k) ap[k * W_] = araw[k] * rs + ps.v[k];
}

// ---------------------------------------------------------------------------
// Pad masks into edge-replicated 144x144 planes.
// ---------------------------------------------------------------------------
__global__ void pad_kernel(const float* __restrict__ src, float* __restrict__ dst,
                           int total) {
  int idx = blockIdx.x * blockDim.x + threadIdx.x;
  if (idx >= total) return;
  int pj = idx % PW_;
  int t  = idx / PW_;
  int pi = t % PH_;
  int p  = t / PH_;
  int i = min(max(pi - PAD_, 0), H_ - 1);
  int j = min(max(pj - PAD_, 0), W_ - 1);
  dst[idx] = src[(size_t)p * (H_ * W_) + i * W_ + j];
}

// ---------------------------------------------------------------------------
// iter_kernel tap macros. Thread owns 2 adjacent quads (8 px) of one row, 3
// channels. PM = (row i-4, col j0), PP = (row i+4, col j0). All offsets are
// compile-time immediates within +-4095 B. All locals are named scalars --
// nothing address-taken, nothing runtime-indexed.
// ---------------------------------------------------------------------------

// horizontal taps, all 4 dilations, one channel (center row = PM + 4*PW_)
#define HCH(PM, ACCa, ACCb) do {                                               \
    f4 m2 = ldq(PM, 4 * PW_ - 8), m1 = ldq(PM, 4 * PW_ - 4);                   \
    f4 c0 = ldq(PM, 4 * PW_),     c1 = ldq(PM, 4 * PW_ + 4);                   \
    f4 c2 = ldq(PM, 4 * PW_ + 8), c3 = ldq(PM, 4 * PW_ + 12);                  \
    ACCa += h1ma * shw<3>(m1, c0) + h1pa * shw<1>(c0, c1);                     \
    ACCb += h1mb * shw<3>(c0, c1) + h1pb * shw<1>(c1, c2);                     \
    ACCa += h2ma * shw<2>(m1, c0) + h2pa * shw<2>(c0, c1);                     \
    ACCb += h2mb * shw<2>(c0, c1) + h2pb * shw<2>(c1, c2);                     \
    ACCa += h4ma * m1 + h4pa * c1;                                             \
    ACCb += h4mb * c0 + h4pb * c2;                                             \
    ACCa += h8ma * m2 + h8pa * c2;                                             \
    ACCb += h8mb * m1 + h8pb * c3;                                             \
  } while (0)

// vertical+diagonal taps, shifted dilation D in {1,2}, SM = 4-D
#define VCHS(D, SM, PM, PP, ACCa, ACCb) do {                                   \
    f4 ua = ldq(PM, (4 - D) * PW_ - 4), ub = ldq(PM, (4 - D) * PW_);           \
    f4 uc = ldq(PM, (4 - D) * PW_ + 4), ud = ldq(PM, (4 - D) * PW_ + 8);       \
    ACCa += A0 * shw<SM>(ua, ub) + A1 * ub + A2 * shw<D>(ub, uc);              \
    ACCb += B0 * shw<SM>(ub, uc) + B1 * uc + B2 * shw<D>(uc, ud);              \
    f4 da = ldq(PP, (D - 4) * PW_ - 4), db = ldq(PP, (D - 4) * PW_);           \
    f4 dc = ldq(PP, (D - 4) * PW_ + 4), dd = ldq(PP, (D - 4) * PW_ + 8);       \
    ACCa += A5 * shw<SM>(da, db) + A6 * db + A7 * shw<D>(db, dc);              \
    ACCb += B5 * shw<SM>(db, dc) + B6 * dc + B7 * shw<D>(dc, dd);              \
  } while (0)

// vertical+diagonal taps, aligned dilation 4 (rows i-4 = PM+0, i+4 = PP+0)
#define VCH4(PM, PP, ACCa, ACCb) do {                                          \
    f4 ua = ldq(PM, -4), ub = ldq(PM, 0), uc = ldq(PM, 4), ud = ldq(PM, 8);    \
    ACCa += A0 * ua + A1 * ub + A2 * uc;                                       \
    ACCb += B0 * ub + B1 * uc + B2 * ud;                                       \
    f4 da = ldq(PP, -4), db = ldq(PP, 0), dc = ldq(PP, 4), dd = ldq(PP, 8);    \
    ACCa += A5 * da + A6 * db + A7 * dc;                                       \
    ACCb += B5 * db + B6 * dc + B7 * dd;                                       \
  } while (0)

// vertical+diagonal taps, aligned dilation 8 (rows i-8 = PM-4*PW_, i+8 = PP+4*PW_)
#define VCH8(PM, PP, ACCa, ACCb) do {                                          \
    f4 u0 = ldq(PM, -4 * PW_ - 8), u1 = ldq(PM, -4 * PW_ - 4);                 \
    f4 u2 = ldq(PM, -4 * PW_),     u3 = ldq(PM, -4 * PW_ + 4);                 \
    f4 u4 = ldq(PM, -4 * PW_ + 8), u5 = ldq(PM, -4 * PW_ + 12);                \
    ACCa += A0 * u0 + A1 * u2 + A2 * u4;                                       \
    ACCb += B0 * u1 + B1 * u3 + B2 * u5;                                       \
    f4 d0 = ldq(PP, 4 * PW_ - 8), d1 = ldq(PP, 4 * PW_ - 4);                   \
    f4 d2 = ldq(PP, 4 * PW_),     d3 = ldq(PP, 4 * PW_ + 4);                   \
    f4 d4 = ldq(PP, 4 * PW_ + 8), d5 = ldq(PP, 4 * PW_ + 12);                  \
    ACCa += A5 * d0 + A6 * d2 + A7 * d4;                                       \
    ACCb += B5 * d1 + B6 * d3 + B7 * d5;                                       \
  } while (0)

// per-dilation vertical aff fragment loads (12 regs), quads a/b
#define AFFV(AB)                                                               \
    f4 A0 = ldq(AB, 0),      B0 = ldq(AB, 4);                                  \
    f4 A1 = ldq(AB, W_),     B1 = ldq(AB, W_ + 4);                             \
    f4 A2 = ldq(AB, 2 * W_), B2 = ldq(AB, 2 * W_ + 4);                         \
    f4 A5 = ldq(AB, 5 * W_), B5 = ldq(AB, 5 * W_ + 4);                         \
    f4 A6 = ldq(AB, 6 * W_), B6 = ldq(AB, 6 * W_ + 4);                         \
    f4 A7 = ldq(AB, 7 * W_), B7 = ldq(AB, 7 * W_ + 4);

// ---------------------------------------------------------------------------
// Propagation step. Block 128 thr = 8 rows x 16 quad-pairs (8 px/thread),
// 3 channels. Grid 896, XCD-pinned: b = bid & 7.
// ---------------------------------------------------------------------------
template <int PADOUT>
__global__ __launch_bounds__(128, 2) void iter_kernel(const float* __restrict__ src,
                                                      const float* __restrict__ aff,
                                                      float* __restrict__ dst) {
  const int bid  = blockIdx.x;
  const int b    = bid & 7;
  const int t    = bid >> 3;
  const int grp  = t % 7;
  const int tile = t / 7;            // 0..15

  const int tid = threadIdx.x;
  const int j0  = (tid & 15) * 8;    // quad pair -> 8 px
  const int i   = tile * 8 + (tid >> 4);
  const int c0  = grp * NC_;

  constexpr int CHP = PH_ * PW_;
  const float* base = src + (size_t)(b * CM_ + c0) * CHP + (i + PAD_) * PW_ + (j0 + PAD_);
  const float* p0m = base           - 4 * PW_;
  const float* p0p = base           + 4 * PW_;
  const float* p1m = base +     CHP - 4 * PW_;
  const float* p1p = base +     CHP + 4 * PW_;
  const float* p2m = base + 2 * CHP - 4 * PW_;
  const float* p2p = base + 2 * CHP + 4 * PW_;

  const float* ab0 = aff + ((size_t)(b * H_ + i) * K_) * W_ + j0;
  const float* ab1 = ab0 +  8 * W_;
  const float* ab2 = ab0 + 16 * W_;
  const float* ab3 = ab0 + 24 * W_;

  f4 acc0a = (f4){0.f,0.f,0.f,0.f}, acc0b = (f4){0.f,0.f,0.f,0.f};
  f4 acc1a = (f4){0.f,0.f,0.f,0.f}, acc1b = (f4){0.f,0.f,0.f,0.f};
  f4 acc2a = (f4){0.f,0.f,0.f,0.f}, acc2b = (f4){0.f,0.f,0.f,0.f};

  // ---- horizontal pass: 16 aff regs + 6 center-row loads per channel
  {
    f4 h1ma = ldq(ab0, 3 * W_), h1mb = ldq(ab0, 3 * W_ + 4);
    f4 h1pa = ldq(ab0, 4 * W_), h1pb = ldq(ab0, 4 * W_ + 4);
    f4 h2ma = ldq(ab1, 3 * W_), h2mb = ldq(ab1, 3 * W_ + 4);
    f4 h2pa = ldq(ab1, 4 * W_), h2pb = ldq(ab1, 4 * W_ + 4);
    f4 h4ma = ldq(ab2, 3 * W_), h4mb = ldq(ab2, 3 * W_ + 4);
    f4 h4pa = ldq(ab2, 4 * W_), h4pb = ldq(ab2, 4 * W_ + 4);
    f4 h8ma = ldq(ab3, 3 * W_), h8mb = ldq(ab3, 3 * W_ + 4);
    f4 h8pa = ldq(ab3, 4 * W_), h8pb = ldq(ab3, 4 * W_ + 4);
    HCH(p0m, acc0a, acc0b);
    HCH(p1m, acc1a, acc1b);
    HCH(p2m, acc2a, acc2b);
  }
  // ---- vertical/diagonal passes, one dilation at a time
  {
    AFFV(ab0);
    VCHS(1, 3, p0m, p0p, acc0a, acc0b);
    VCHS(1, 3, p1m, p1p, acc1a, acc1b);
    VCHS(1, 3, p2m, p2p, acc2a, acc2b);
  }
  {
    AFFV(ab1);
    VCHS(2, 2, p0m, p0p, acc0a, acc0b);
    VCHS(2, 2, p1m, p1p, acc1a, acc1b);
    VCHS(2, 2, p2m, p2p, acc2a, acc2b);
  }
  {
    AFFV(ab2);
    VCH4(p0m, p0p, acc0a, acc0b);
    VCH4(p1m, p1p, acc1a, acc1b);
    VCH4(p2m, p2p, acc2a, acc2b);
  }
  {
    AFFV(ab3);
    VCH8(p0m, p0p, acc0a, acc0b);
    VCH8(p1m, p1p, acc1a, acc1b);
    VCH8(p2m, p2p, acc2a, acc2b);
  }

  // ---- epilogue
  if (PADOUT) {
    const int pr = i + PAD_;
    const int r0 = (i == 0)      ? 0         : pr;
    const int r1 = (i == H_ - 1) ? (PH_ - 1) : pr;
    float* d0 = dst + ((size_t)(b * CM_ + c0 + 0)) * CHP;
    float* d1 = dst + ((size_t)(b * CM_ + c0 + 1)) * CHP;
    float* d2 = dst + ((size_t)(b * CM_ + c0 + 2)) * CHP;
    for (int r = r0; r <= r1; ++r) {
      float* row0 = d0 + r * PW_;
      float* row1 = d1 + r * PW_;
      float* row2 = d2 + r * PW_;
      *reinterpret_cast<f4*>(row0 + PAD_ + j0) = acc0a;
      *reinterpret_cast<f4*>(row0 + PAD_ + j0 + 4) = acc0b;
      *reinterpret_cast<f4*>(row1 + PAD_ + j0) = acc1a;
      *reinterpret_cast<f4*>(row1 + PAD_ + j0 + 4) = acc1b;
      *reinterpret_cast<f4*>(row2 + PAD_ + j0) = acc2a;
      *reinterpret_cast<f4*>(row2 + PAD_ + j0 + 4) = acc2b;
      if (j0 == 0) {
        f4 s0 = (f4){acc0a.x, acc0a.x, acc0a.x, acc0a.x};
        f4 s1 = (f4){acc1a.x, acc1a.x, acc1a.x, acc1a.x};
        f4 s2 = (f4){acc2a.x, acc2a.x, acc2a.x, acc2a.x};
        *reinterpret_cast<f4*>(row0) = s0; *reinterpret_cast<f4*>(row0 + 4) = s0;
        *reinterpret_cast<f4*>(row1) = s1; *reinterpret_cast<f4*>(row1 + 4) = s1;
        *reinterpret_cast<f4*>(row2) = s2; *reinterpret_cast<f4*>(row2 + 4) = s2;
      }
      if (j0 == W_ - 8) {
        f4 s0 = (f4){acc0b.w, acc0b.w, acc0b.w, acc0b.w};
        f4 s1 = (f4){acc1b.w, acc1b.w, acc1b.w, acc1b.w};
        f4 s2 = (f4){acc2b.w, acc2b.w, acc2b.w, acc2b.w};
        *reinterpret_cast<f4*>(row0 + PW_ - 8) = s0; *reinterpret_cast<f4*>(row0 + PW_ - 4) = s0;
        *reinterpret_cast<f4*>(row1 + PW_ - 8) = s1; *reinterpret_cast<f4*>(row1 + PW_ - 4) = s1;
        *reinterpret_cast<f4*>(row2 + PW_ - 8) = s2; *reinterpret_cast<f4*>(row2 + PW_ - 4) = s2;
      }
    }
  } else {
    float* dc = dst + ((size_t)(b * CM_ + c0)) * (H_ * W_) + (size_t)i * W_ + j0;
    *reinterpret_cast<f4*>(dc)                     = acc0a;
    *reinterpret_cast<f4*>(dc + 4)                 = acc0b;
    *reinterpret_cast<f4*>(dc +     (H_ * W_))     = acc1a;
    *reinterpret_cast<f4*>(dc +     (H_ * W_) + 4) = acc1b;
    *reinterpret_cast<f4*>(dc + 2 * (H_ * W_))     = acc2a;
    *reinterpret_cast<f4*>(dc + 2 * (H_ * W_) + 4) = acc2b;
  }
}

// ---------------------------------------------------------------------------
extern "C" void kernel_launch(void* const* d_in, const int* in_sizes, int n_in,
                              void* d_out, int out_size, void* d_ws, size_t ws_size,
                              hipStream_t stream) {
  const float* imgs  = (const float*)d_in[0];
  const float* masks = (const float*)d_in[1];
  float* out = (float*)d_out;

  char* ws = (char*)d_ws;
  const size_t affBytes = (size_t)B_ * K_ * H_ * W_ * sizeof(float);
  const size_t padBytes = (size_t)B_ * CM_ * PH_ * PW_ * sizeof(float);
  float* aff = (float*)ws;
  float* P0  = (float*)(ws + affBytes);
  float* P1  = (float*)(ws + affBytes + padBytes);

  PosSoft ps;
  {
    const double pv[8] = {1.4142135623730951, 1.0, 1.4142135623730951, 1.0,
                          1.0, 1.4142135623730951, 1.0, 1.4142135623730951};
    double pos[K_];
    for (int di = 0; di < 4; ++di) {
      double d = (double)(1 << di);
      for (int o = 0; o < 8; ++o) pos[di * 8 + o] = pv[o] * d;
    }
    double mean = 0; for (int k = 0; k < K_; ++k) mean += pos[k]; mean /= K_;
    double var = 0;  for (int k = 0; k < K_; ++k) { double dd = pos[k] - mean; var += dd * dd; }
    var /= (K_ - 1);
    double sd = sqrt(var);
    double pa[K_]; double m = -1e300;
    for (int k = 0; k < K_; ++k) {
      double r = pos[k] / ((sd + 1e-8) * 0.3);
      pa[k] = -(r * r);
      if (pa[k] > m) m = pa[k];
    }
    double es = 0; for (int k = 0; k < K_; ++k) { pa[k] = exp(pa[k] - m); es += pa[k]; }
    for (int k = 0; k < K_; ++k) ps.v[k] = (float)(0.01 * pa[k] / es);
  }

  aff_kernel<<<dim3(H_, B_), 128, 0, stream>>>(imgs, aff, ps);

  const int total = B_ * CM_ * PH_ * PW_;
  pad_kernel<<<(total + 255) / 256, 256, 0, stream>>>(masks, P0, total);

  const int nblk = B_ * 7 * (H_ / 8);   // 896, XCD-pinned decode in kernel
  float* s = P0;
  float* d = P1;
  for (int it = 0; it < 9; ++it) {
    iter_kernel<1><<<nblk, 128, 0, stream>>>(s, aff, d);
    float* t = s; s = d; d = t;
  }
  iter_kernel<0><<<nblk, 128, 0, stream>>>(s, aff, out);
}

// Round 6
// 179.046 us; speedup vs baseline: 8.1640x; 1.2837x over previous
//
#include <hip/hip_runtime.h>
#include <cmath>

#define B_   8
#define CI_  3
#define CM_  21
#define H_   128
#define W_   128
#define K_   32
#define PAD_ 8
#define PW_  144
#define PH_  144
#define NC_  3   // mask channels per block in iter kernel (21 = 7 groups of 3)

typedef float f4 __attribute__((ext_vector_type(4)));
typedef _Float16 h4 __attribute__((ext_vector_type(4)));

struct PosSoft { float v[K_]; };

// shifted window: elements [S .. S+3] of concat(A,B); pure register selection.
template<int S>
__device__ __forceinline__ f4 shw(f4 A, f4 B) {
  if constexpr (S == 0) return A;
  else if constexpr (S == 1) return (f4){A.y, A.z, A.w, B.x};
  else if constexpr (S == 2) return (f4){A.z, A.w, B.x, B.y};
  else                       return (f4){A.w, B.x, B.y, B.z};
}

// aligned f4 load at compile-time float offset -> single global_load_dwordx4
__device__ __forceinline__ f4 ldq(const float* p, int off) {
  return *reinterpret_cast<const f4*>(p + off);
}
// aligned h4 load (8 B, full-line coalesced) + widen to f4
__device__ __forceinline__ f4 ldh(const _Float16* p, int off) {
  return __builtin_convertvector(*reinterpret_cast<const h4*>(p + off), f4);
}

// ---------------------------------------------------------------------------
// Phase A: per-pixel affinity (softmax over K=32) + constant position term.
// Output layout: aff[b][i][k][j]  (k-major per row, j contiguous), f32.
// ---------------------------------------------------------------------------
__global__ __launch_bounds__(128) void aff_kernel(const float* __restrict__ imgs,
                                                  float* __restrict__ aff,
                                                  PosSoft ps) {
  constexpr int OI[8] = {-1,-1,-1, 0, 0, 1, 1, 1};
  constexpr int OJ[8] = {-1, 0, 1,-1, 1,-1, 0, 1};
  const int j = threadIdx.x;
  const int i = blockIdx.x;
  const int b = blockIdx.y;
  const float* img = imgs + (size_t)b * CI_ * H_ * W_;

  float ctr[CI_];
#pragma unroll
  for (int c = 0; c < CI_; ++c) ctr[c] = img[c * H_ * W_ + i * W_ + j];

  float s[CI_] = {0.f, 0.f, 0.f}, s2[CI_] = {0.f, 0.f, 0.f};
#pragma unroll
  for (int k = 0; k < K_; ++k) {
    const int d  = 1 << (k >> 3);
    const int ci = min(max(i + OI[k & 7] * d, 0), H_ - 1);
    const int cj = min(max(j + OJ[k & 7] * d, 0), W_ - 1);
#pragma unroll
    for (int c = 0; c < CI_; ++c) {
      float v = img[c * H_ * W_ + ci * W_ + cj];
      s[c] += v; s2[c] += v * v;
    }
  }

  float inv[CI_];
#pragma unroll
  for (int c = 0; c < CI_; ++c) {
    float mean = s[c] * (1.f / K_);
    float var  = (s2[c] - (float)K_ * mean * mean) * (1.f / (K_ - 1));
    var = fmaxf(var, 0.f);
    inv[c] = 1.f / ((sqrtf(var) + 1e-8f) * 0.3f);
  }

  float araw[K_];
#pragma unroll
  for (int k = 0; k < K_; ++k) {
    const int d  = 1 << (k >> 3);
    const int ci = min(max(i + OI[k & 7] * d, 0), H_ - 1);
    const int cj = min(max(j + OJ[k & 7] * d, 0), W_ - 1);
    float t = 0.f;
#pragma unroll
    for (int c = 0; c < CI_; ++c) {
      float v  = img[c * H_ * W_ + ci * W_ + cj];
      float dd = fabsf(v - ctr[c]) * inv[c];
      t += dd * dd;
    }
    araw[k] = -t * (1.f / CI_);
  }

  float m = araw[0];
#pragma unroll
  for (int k = 1; k < K_; ++k) m = fmaxf(m, araw[k]);
  float sum = 0.f;
#pragma unroll
  for (int k = 0; k < K_; ++k) { float e = __expf(araw[k] - m); araw[k] = e; sum += e; }
  const float rs = 1.f / sum;

  float* ap = aff + ((size_t)(b * H_ + i) * K_) * W_ + j;
#pragma unroll
  for (int k = 0; k < K_; ++k) ap[k * W_] = araw[k] * rs + ps.v[k];
}

// ---------------------------------------------------------------------------
// Pad masks into edge-replicated 144x144 fp16 planes. One h4 slot per thread.
// ---------------------------------------------------------------------------
__global__ void pad_kernel(const float* __restrict__ src, _Float16* __restrict__ dst,
                           int total4) {
  int idx = blockIdx.x * blockDim.x + threadIdx.x;
  if (idx >= total4) return;
  int q  = idx % (PW_ / 4);
  int t  = idx / (PW_ / 4);
  int pi = t % PH_;
  int p  = t / PH_;
  int i = min(max(pi - PAD_, 0), H_ - 1);
  const float* srow = src + (size_t)p * (H_ * W_) + i * W_;
  h4 o;
#pragma unroll
  for (int e = 0; e < 4; ++e) {
    int j = min(max(q * 4 + e - PAD_, 0), W_ - 1);
    o[e] = (_Float16)srow[j];
  }
  *reinterpret_cast<h4*>(dst + (size_t)p * (PH_ * PW_) + pi * PW_ + q * 4) = o;
}

// ---------------------------------------------------------------------------
// iter_kernel tap macros. Thread owns 4 px of one row, 3 channels. PM = (row
// i-4, col j0), PP = (row i+4, col j0), offsets in HALF units (PW_=144). All
// compile-time immediates; all locals named scalars (nothing address-taken).
// ---------------------------------------------------------------------------

// horizontal taps, all 4 dilations, one channel (center row = PM + 4*PW_)
#define HCH(PM, ACC) do {                                                      \
    f4 m2 = ldh(PM, 4 * PW_ - 8), m1 = ldh(PM, 4 * PW_ - 4);                   \
    f4 c0 = ldh(PM, 4 * PW_),     c1 = ldh(PM, 4 * PW_ + 4);                   \
    f4 c2 = ldh(PM, 4 * PW_ + 8);                                              \
    ACC += h1m * shw<3>(m1, c0) + h1p * shw<1>(c0, c1);                        \
    ACC += h2m * shw<2>(m1, c0) + h2p * shw<2>(c0, c1);                        \
    ACC += h4m * m1 + h4p * c1;                                                \
    ACC += h8m * m2 + h8p * c2;                                                \
  } while (0)

// vertical+diagonal taps, shifted dilation D in {1,2}, SM = 4-D
#define VCHS(D, SM, PM, PP, ACC) do {                                          \
    f4 ua = ldh(PM, (4 - D) * PW_ - 4), ub = ldh(PM, (4 - D) * PW_);           \
    f4 uc = ldh(PM, (4 - D) * PW_ + 4);                                        \
    ACC += A0 * shw<SM>(ua, ub) + A1 * ub + A2 * shw<D>(ub, uc);               \
    f4 da = ldh(PP, (D - 4) * PW_ - 4), db = ldh(PP, (D - 4) * PW_);           \
    f4 dc = ldh(PP, (D - 4) * PW_ + 4);                                        \
    ACC += A5 * shw<SM>(da, db) + A6 * db + A7 * shw<D>(db, dc);               \
  } while (0)

// vertical+diagonal taps, aligned dilation 4
#define VCH4(PM, PP, ACC) do {                                                 \
    f4 ua = ldh(PM, -4), ub = ldh(PM, 0), uc = ldh(PM, 4);                     \
    ACC += A0 * ua + A1 * ub + A2 * uc;                                        \
    f4 da = ldh(PP, -4), db = ldh(PP, 0), dc = ldh(PP, 4);                     \
    ACC += A5 * da + A6 * db + A7 * dc;                                        \
  } while (0)

// vertical+diagonal taps, aligned dilation 8 (rows i-8 / i+8)
#define VCH8(PM, PP, ACC) do {                                                 \
    f4 ua = ldh(PM, -4 * PW_ - 8), ub = ldh(PM, -4 * PW_);                     \
    f4 uc = ldh(PM, -4 * PW_ + 8);                                             \
    ACC += A0 * ua + A1 * ub + A2 * uc;                                        \
    f4 da = ldh(PP, 4 * PW_ - 8), db = ldh(PP, 4 * PW_);                       \
    f4 dc = ldh(PP, 4 * PW_ + 8);                                              \
    ACC += A5 * da + A6 * db + A7 * dc;                                        \
  } while (0)

// per-dilation vertical aff fragment loads (6 regs, f32, full-line)
#define AFFV(AB)                                                               \
    f4 A0 = ldq(AB, 0),      A1 = ldq(AB, W_),     A2 = ldq(AB, 2 * W_);       \
    f4 A5 = ldq(AB, 5 * W_), A6 = ldq(AB, 6 * W_), A7 = ldq(AB, 7 * W_);

// ---------------------------------------------------------------------------
// Propagation step. Block 128 thr = 4 rows x 32 col-quads (4 px/thread),
// 3 channels. Grid 1792, XCD-pinned: b = bid & 7. fp16 mask planes, f32 aff,
// f32 accumulation. PADOUT=1 -> half padded dst; PADOUT=0 -> f32 d_out.
// ---------------------------------------------------------------------------
template <int PADOUT>
__global__ __launch_bounds__(128, 3) void iter_kernel(const _Float16* __restrict__ src,
                                                      const float* __restrict__ aff,
                                                      void* __restrict__ dstv) {
  const int bid  = blockIdx.x;
  const int b    = bid & 7;
  const int t    = bid >> 3;
  const int grp  = t % 7;
  const int tile = t / 7;

  const int tid = threadIdx.x;
  const int j0  = (tid & 31) * 4;
  const int i   = tile * 4 + (tid >> 5);
  const int c0  = grp * NC_;

  constexpr int CHP = PH_ * PW_;
  const _Float16* base = src + (size_t)(b * CM_ + c0) * CHP + (i + PAD_) * PW_ + (j0 + PAD_);
  const _Float16* p0m = base           - 4 * PW_;
  const _Float16* p0p = base           + 4 * PW_;
  const _Float16* p1m = base +     CHP - 4 * PW_;
  const _Float16* p1p = base +     CHP + 4 * PW_;
  const _Float16* p2m = base + 2 * CHP - 4 * PW_;
  const _Float16* p2p = base + 2 * CHP + 4 * PW_;

  const float* ab0 = aff + ((size_t)(b * H_ + i) * K_) * W_ + j0;
  const float* ab1 = ab0 +  8 * W_;
  const float* ab2 = ab0 + 16 * W_;
  const float* ab3 = ab0 + 24 * W_;

  f4 acc0 = (f4){0.f, 0.f, 0.f, 0.f};
  f4 acc1 = (f4){0.f, 0.f, 0.f, 0.f};
  f4 acc2 = (f4){0.f, 0.f, 0.f, 0.f};

  // ---- horizontal pass: 8 aff regs + 5 center-row loads per channel
  {
    f4 h1m = ldq(ab0, 3 * W_), h1p = ldq(ab0, 4 * W_);
    f4 h2m = ldq(ab1, 3 * W_), h2p = ldq(ab1, 4 * W_);
    f4 h4m = ldq(ab2, 3 * W_), h4p = ldq(ab2, 4 * W_);
    f4 h8m = ldq(ab3, 3 * W_), h8p = ldq(ab3, 4 * W_);
    HCH(p0m, acc0);
    HCH(p1m, acc1);
    HCH(p2m, acc2);
  }
  // ---- vertical/diagonal passes, one dilation at a time
  {
    AFFV(ab0);
    VCHS(1, 3, p0m, p0p, acc0);
    VCHS(1, 3, p1m, p1p, acc1);
    VCHS(1, 3, p2m, p2p, acc2);
  }
  {
    AFFV(ab1);
    VCHS(2, 2, p0m, p0p, acc0);
    VCHS(2, 2, p1m, p1p, acc1);
    VCHS(2, 2, p2m, p2p, acc2);
  }
  {
    AFFV(ab2);
    VCH4(p0m, p0p, acc0);
    VCH4(p1m, p1p, acc1);
    VCH4(p2m, p2p, acc2);
  }
  {
    AFFV(ab3);
    VCH8(p0m, p0p, acc0);
    VCH8(p1m, p1p, acc1);
    VCH8(p2m, p2p, acc2);
  }

  // ---- epilogue
  if (PADOUT) {
    _Float16* d0 = (_Float16*)dstv + (size_t)(b * CM_ + c0) * CHP;
    _Float16* d1 = d0 + CHP;
    _Float16* d2 = d0 + 2 * CHP;
    h4 o0 = __builtin_convertvector(acc0, h4);
    h4 o1 = __builtin_convertvector(acc1, h4);
    h4 o2 = __builtin_convertvector(acc2, h4);
    const int pr = i + PAD_;
    const int r0 = (i == 0)      ? 0         : pr;
    const int r1 = (i == H_ - 1) ? (PH_ - 1) : pr;
    for (int r = r0; r <= r1; ++r) {
      _Float16* row0 = d0 + r * PW_;
      _Float16* row1 = d1 + r * PW_;
      _Float16* row2 = d2 + r * PW_;
      *reinterpret_cast<h4*>(row0 + PAD_ + j0) = o0;
      *reinterpret_cast<h4*>(row1 + PAD_ + j0) = o1;
      *reinterpret_cast<h4*>(row2 + PAD_ + j0) = o2;
      if (j0 == 0) {
        h4 s0 = (h4){o0.x, o0.x, o0.x, o0.x};
        h4 s1 = (h4){o1.x, o1.x, o1.x, o1.x};
        h4 s2 = (h4){o2.x, o2.x, o2.x, o2.x};
        *reinterpret_cast<h4*>(row0) = s0; *reinterpret_cast<h4*>(row0 + 4) = s0;
        *reinterpret_cast<h4*>(row1) = s1; *reinterpret_cast<h4*>(row1 + 4) = s1;
        *reinterpret_cast<h4*>(row2) = s2; *reinterpret_cast<h4*>(row2 + 4) = s2;
      }
      if (j0 == W_ - 4) {
        h4 s0 = (h4){o0.w, o0.w, o0.w, o0.w};
        h4 s1 = (h4){o1.w, o1.w, o1.w, o1.w};
        h4 s2 = (h4){o2.w, o2.w, o2.w, o2.w};
        *reinterpret_cast<h4*>(row0 + PW_ - 8) = s0; *reinterpret_cast<h4*>(row0 + PW_ - 4) = s0;
        *reinterpret_cast<h4*>(row1 + PW_ - 8) = s1; *reinterpret_cast<h4*>(row1 + PW_ - 4) = s1;
        *reinterpret_cast<h4*>(row2 + PW_ - 8) = s2; *reinterpret_cast<h4*>(row2 + PW_ - 4) = s2;
      }
    }
  } else {
    float* dc = (float*)dstv + (size_t)(b * CM_ + c0) * (H_ * W_) + (size_t)i * W_ + j0;
    *reinterpret_cast<f4*>(dc)                 = acc0;
    *reinterpret_cast<f4*>(dc +     (H_ * W_)) = acc1;
    *reinterpret_cast<f4*>(dc + 2 * (H_ * W_)) = acc2;
  }
}

// ---------------------------------------------------------------------------
extern "C" void kernel_launch(void* const* d_in, const int* in_sizes, int n_in,
                              void* d_out, int out_size, void* d_ws, size_t ws_size,
                              hipStream_t stream) {
  const float* imgs  = (const float*)d_in[0];
  const float* masks = (const float*)d_in[1];
  float* out = (float*)d_out;

  char* ws = (char*)d_ws;
  const size_t affBytes = (size_t)B_ * K_ * H_ * W_ * sizeof(float);        // 16.8 MB
  const size_t padBytes = (size_t)B_ * CM_ * PH_ * PW_ * sizeof(_Float16);  // 7.0 MB
  float*    aff = (float*)ws;
  _Float16* P0  = (_Float16*)(ws + affBytes);
  _Float16* P1  = (_Float16*)(ws + affBytes + padBytes);

  PosSoft ps;
  {
    const double pv[8] = {1.4142135623730951, 1.0, 1.4142135623730951, 1.0,
                          1.0, 1.4142135623730951, 1.0, 1.4142135623730951};
    double pos[K_];
    for (int di = 0; di < 4; ++di) {
      double d = (double)(1 << di);
      for (int o = 0; o < 8; ++o) pos[di * 8 + o] = pv[o] * d;
    }
    double mean = 0; for (int k = 0; k < K_; ++k) mean += pos[k]; mean /= K_;
    double var = 0;  for (int k = 0; k < K_; ++k) { double dd = pos[k] - mean; var += dd * dd; }
    var /= (K_ - 1);
    double sd = sqrt(var);
    double pa[K_]; double m = -1e300;
    for (int k = 0; k < K_; ++k) {
      double r = pos[k] / ((sd + 1e-8) * 0.3);
      pa[k] = -(r * r);
      if (pa[k] > m) m = pa[k];
    }
    double es = 0; for (int k = 0; k < K_; ++k) { pa[k] = exp(pa[k] - m); es += pa[k]; }
    for (int k = 0; k < K_; ++k) ps.v[k] = (float)(0.01 * pa[k] / es);
  }

  aff_kernel<<<dim3(H_, B_), 128, 0, stream>>>(imgs, aff, ps);

  const int total4 = B_ * CM_ * PH_ * (PW_ / 4);
  pad_kernel<<<(total4 + 255) / 256, 256, 0, stream>>>(masks, P0, total4);

  const int nblk = B_ * 7 * (H_ / 4);   // 1792, XCD-pinned decode in kernel
  _Float16* s = P0;
  _Float16* d = P1;
  for (int it = 0; it < 9; ++it) {
    iter_kernel<1><<<nblk, 128, 0, stream>>>(s, aff, (void*)d);
    _Float16* tm = s; s = d; d = tm;
  }
  iter_kernel<0><<<nblk, 128, 0, stream>>>(s, aff, (void*)out);
}